// Round 9
// baseline (221.601 us; speedup 1.0000x reference)
//
#include <hip/hip_runtime.h>
#include <hip/hip_fp16.h>
#include <math.h>

// Problem constants (from reference)
constexpr int Nn  = 50000;   // nodes
constexpr int FIN = 128;     // input features
constexpr int NH  = 8;       // heads
constexpr int FO  = 16;      // features per head
constexpr int HF  = 128;     // NH*FO
constexpr int NWR = 272;     // Wh rows: Wp(128) | Wskip(128) | Va_src(8) | Va_trg(8)
constexpr int NSCAN = (Nn + 255) / 256;         // 196 scan blocks

typedef _Float16 f16x8 __attribute__((ext_vector_type(8)));
typedef float    f32x4 __attribute__((ext_vector_type(4)));

// ---------------------------------------------------------------------------
// Weight prep: Wh[272][128] f16 =
//   rows   0..127 : Wp
//   rows 128..255 : Wskip
//   rows 256..263 : Va_src[h][k] = sum_f a_src[h,f] * Wp[h*16+f][k]
//   rows 264..271 : Va_trg[h][k] = sum_f a_trg[h,f] * Wp[h*16+f][k]
// ---------------------------------------------------------------------------
__global__ __launch_bounds__(128) void k_prep(
    const float* __restrict__ Wp, const float* __restrict__ Wskip,
    const float* __restrict__ a_src, const float* __restrict__ a_trg,
    _Float16* __restrict__ Wh)
{
    const int o = blockIdx.x;   // 0..271
    const int k = threadIdx.x;  // 0..127
    float v;
    if (o < 128)      v = Wp[o * FIN + k];
    else if (o < 256) v = Wskip[(o - 128) * FIN + k];
    else if (o < 264) {
        const int h = o - 256;
        float s = 0.f;
        #pragma unroll
        for (int f = 0; f < FO; ++f)
            s += a_src[h * FO + f] * Wp[(h * FO + f) * FIN + k];
        v = s;
    } else {
        const int h = o - 264;
        float s = 0.f;
        #pragma unroll
        for (int f = 0; f < FO; ++f)
            s += a_trg[h * FO + f] * Wp[(h * FO + f) * FIN + k];
        v = s;
    }
    Wh[o * FIN + k] = (_Float16)v;
}

// ---------------------------------------------------------------------------
// Node GEMM via MFMA f16: one wave per 16-node stripe, C = x @ Wh^T.
// 17 N-tiles x 4 K-steps = 68 mfma_f32_16x16x32_f16.
// Epilogue: projG[g][n][hh][f] f16 (group-major, 64B per node per group),
//           out = skip + bias,
//           ssg[g][n][hh] / stg[g][n][hh] f32 score arrays (group-packed).
// ---------------------------------------------------------------------------
__global__ __launch_bounds__(64) void k_node(
    const float* __restrict__ x, const _Float16* __restrict__ Wh,
    const float* __restrict__ bias,
    __half* __restrict__ projG, float* __restrict__ out,
    float* __restrict__ ssg, float* __restrict__ stg)
{
    const int n0 = blockIdx.x * 16;            // 3125 * 16 = 50000 exactly
    const int l  = threadIdx.x;                // 0..63
    const int lr = l & 15;
    const int kb = l >> 4;                     // k-block 0..3

    f16x8 a[4];
    const float* xr = x + (size_t)(n0 + lr) * FIN + kb * 8;
    #pragma unroll
    for (int ks = 0; ks < 4; ++ks) {
        float4 u0 = *reinterpret_cast<const float4*>(xr + ks * 32);
        float4 u1 = *reinterpret_cast<const float4*>(xr + ks * 32 + 4);
        a[ks][0] = (_Float16)u0.x; a[ks][1] = (_Float16)u0.y;
        a[ks][2] = (_Float16)u0.z; a[ks][3] = (_Float16)u0.w;
        a[ks][4] = (_Float16)u1.x; a[ks][5] = (_Float16)u1.y;
        a[ks][6] = (_Float16)u1.z; a[ks][7] = (_Float16)u1.w;
    }

    f32x4 acc[17];
    #pragma unroll
    for (int t = 0; t < 17; ++t) acc[t] = (f32x4){0.f, 0.f, 0.f, 0.f};

    const _Float16* wb = Wh + (size_t)lr * FIN + kb * 8;
    #pragma unroll
    for (int t = 0; t < 17; ++t) {
        const _Float16* wt = wb + (size_t)t * 16 * FIN;
        #pragma unroll
        for (int ks = 0; ks < 4; ++ks) {
            f16x8 b = *reinterpret_cast<const f16x8*>(wt + ks * 32);
            acc[t] = __builtin_amdgcn_mfma_f32_16x16x32_f16(a[ks], b, acc[t], 0, 0, 0);
        }
    }

    #pragma unroll
    for (int r = 0; r < 4; ++r) {
        const int n = n0 + kb * 4 + r;
        // proj heads (tiles 0..7): group g = t>>1, head-in-group hh = t&1
        #pragma unroll
        for (int t = 0; t < 8; ++t)
            projG[((size_t)(t >> 1) * Nn + n) * 32 + (t & 1) * 16 + lr] =
                __float2half_rn(acc[t][r]);
        // skip + bias (tiles 8..15) -> output accumulator
        #pragma unroll
        for (int t = 8; t < 16; ++t) {
            const int o = (t - 8) * 16 + lr;
            out[(size_t)n * HF + o] = acc[t][r] + bias[o];
        }
        // score tile 16: cols 0..7 = s_src per head, 8..15 = s_trg per head
        {
            const float v = acc[16][r];
            if (lr < 8)
                ssg[(size_t)(lr >> 1) * 2 * Nn + n * 2 + (lr & 1)] = v;
            else
                stg[(size_t)((lr - 8) >> 1) * 2 * Nn + n * 2 + ((lr - 8) & 1)] = v;
        }
    }
}

// ---------------------------------------------------------------------------
// CSR count (by target); block 0 also computes ctp[h] = <Wt[h,:], a_tp[h,:]>
// ---------------------------------------------------------------------------
__global__ __launch_bounds__(256) void k_count(const int* __restrict__ trg,
                                               int* __restrict__ deg,
                                               const float* __restrict__ Wt,
                                               const float* __restrict__ a_tp,
                                               float* __restrict__ ctp, int E)
{
    if (blockIdx.x == 0 && threadIdx.x < NH) {
        int h = threadIdx.x;
        float s = 0.f;
        #pragma unroll
        for (int f = 0; f < FO; ++f) s += Wt[h * FO + f] * a_tp[h * FO + f];
        ctp[h] = s;
    }
    int e4 = blockIdx.x * blockDim.x + threadIdx.x;
    if (e4 * 4 < E) {
        int4 t = reinterpret_cast<const int4*>(trg)[e4];
        atomicAdd(&deg[t.x], 1);
        atomicAdd(&deg[t.y], 1);
        atomicAdd(&deg[t.z], 1);
        atomicAdd(&deg[t.w], 1);
    }
}

// ---------------------------------------------------------------------------
// Scan: per-block sums, then fused (redundant block-scan of partials) +
// per-element exclusive scan -> pos.
// ---------------------------------------------------------------------------
__global__ __launch_bounds__(256) void k_scan1(const int* __restrict__ deg,
                                               int* __restrict__ partial)
{
    __shared__ int lds[256];
    int t = threadIdx.x, i = blockIdx.x * 256 + t;
    lds[t] = (i < Nn) ? deg[i] : 0;
    __syncthreads();
    for (int off = 128; off > 0; off >>= 1) {
        if (t < off) lds[t] += lds[t + off];
        __syncthreads();
    }
    if (t == 0) partial[blockIdx.x] = lds[0];
}

__global__ __launch_bounds__(256) void k_scan3(const int* __restrict__ deg,
                                               const int* __restrict__ partial,
                                               int* __restrict__ pos)
{
    __shared__ int lds[256], lds2[256];
    const int t = threadIdx.x;
    const int i = blockIdx.x * 256 + t;
    lds2[t] = (t < NSCAN) ? partial[t] : 0;
    __syncthreads();
    for (int off = 1; off < 256; off <<= 1) {
        int u = (t >= off) ? lds2[t - off] : 0;
        __syncthreads();
        lds2[t] += u;
        __syncthreads();
    }
    const int base = (blockIdx.x == 0) ? 0 : lds2[blockIdx.x - 1];
    int v = (i < Nn) ? deg[i] : 0;
    lds[t] = v;
    __syncthreads();
    for (int off = 1; off < 256; off <<= 1) {
        int u = (t >= off) ? lds[t - off] : 0;
        __syncthreads();
        lds[t] += u;
        __syncthreads();
    }
    if (i < Nn) pos[i] = base + lds[t] - v;
}

// fill: pos[n] bumps exclusive -> inclusive; row n spans
// [ (n ? pos[n-1] : 0), pos[n] ).  spk = src(16b) | f16(prob)(16b), 4B/edge.
__global__ __launch_bounds__(256) void k_fill(
    const int* __restrict__ src, const int* __restrict__ trg,
    const float* __restrict__ prob, int* __restrict__ pos,
    unsigned int* __restrict__ spk, int E)
{
    int e4 = blockIdx.x * blockDim.x + threadIdx.x;
    if (e4 * 4 >= E) return;
    int4   s4 = reinterpret_cast<const int4*>(src)[e4];
    int4   t4 = reinterpret_cast<const int4*>(trg)[e4];
    float4 p4 = reinterpret_cast<const float4*>(prob)[e4];
    int    sv[4] = {s4.x, s4.y, s4.z, s4.w};
    int    tv[4] = {t4.x, t4.y, t4.z, t4.w};
    float  pv[4] = {p4.x, p4.y, p4.z, p4.w};
    #pragma unroll
    for (int i = 0; i < 4; ++i) {
        int slot = atomicAdd(&pos[tv[i]], 1);
        spk[slot] = (unsigned int)sv[i] |
            ((unsigned int)__half_as_ushort(__float2half_rn(pv[i])) << 16);
    }
}

// ---------------------------------------------------------------------------
// Fused gather, 2-head groups XCD-pinned: g = bid & 3 (group g runs on XCDs
// {g, g+4}; per-XCD resident set = projG slice 3.2MB + ssg 0.4MB < 4MB L2).
// One wave per (node, group); lanes = 4 edge-slots x 2 heads x 8 f-pairs.
// Per edge: spk dword + ssg f32 gather + 64B contiguous projG slot-read;
// score+exp inline. Reduce = 2 shuffle rounds across slots.
// ---------------------------------------------------------------------------
__global__ __launch_bounds__(256) void k_gather(
    const unsigned int* __restrict__ spk, const int* __restrict__ pos,
    const float* __restrict__ ssg, const float* __restrict__ stg,
    const float* __restrict__ ctp, const __half2* __restrict__ projG,
    float* __restrict__ out)
{
    const int bid = blockIdx.x;
    const int g   = bid & 3;                   // head-group, XCD-pinned
    const int nb  = bid >> 2;                  // 0..12499
    const int wv   = threadIdx.x >> 6;
    const int n    = nb * 4 + wv;              // 12500*4 = 50000 exactly
    const int lane = threadIdx.x & 63;
    const int slot = lane >> 4;                // edge slot 0..3
    const int hh   = (lane >> 3) & 1;          // head within group
    const int f2   = lane & 7;                 // feature pair 0..7

    const int jb = (n == 0) ? 0 : pos[n - 1];
    const int je = pos[n];
    const float st  = stg[(size_t)g * 2 * Nn + n * 2 + hh];
    const float cth = ctp[g * 2 + hh];
    const float* __restrict__ ss = ssg + (size_t)g * 2 * Nn + hh;   // [s*2]
    const __half2* __restrict__ pG = projG + (size_t)g * Nn * 16 + hh * 8 + f2; // [s*16]

    float num0 = 0.f, num1 = 0.f, den = 0.f;
    int j = jb + slot;
    for (; j + 4 < je; j += 8) {               // 2 independent chains
        const unsigned int pk0 = spk[j];
        const unsigned int pk1 = spk[j + 4];
        const int s0 = pk0 & 0xFFFF;
        const int s1 = pk1 & 0xFFFF;
        const float p0 = __half2float(__ushort_as_half((unsigned short)(pk0 >> 16)));
        const float p1 = __half2float(__ushort_as_half((unsigned short)(pk1 >> 16)));
        const float ss0 = ss[s0 * 2];
        const float ss1 = ss[s1 * 2];
        const __half2 g0 = pG[s0 * 16];
        const __half2 g1 = pG[s1 * 16];
        float sc0 = ss0 + st + cth * p0;
        float sc1 = ss1 + st + cth * p1;
        sc0 = fmaxf(sc0, 0.2f * sc0);          // leaky_relu(0.2)
        sc1 = fmaxf(sc1, 0.2f * sc1);
        const float ev0 = __expf(sc0);
        const float ev1 = __expf(sc1);
        const float2 G0 = __half22float2(g0);
        const float2 G1 = __half22float2(g1);
        den  += ev0 + ev1;
        num0 += ev0 * G0.x + ev1 * G1.x;
        num1 += ev0 * G0.y + ev1 * G1.y;
    }
    if (j < je) {
        const unsigned int pk = spk[j];
        const int s = pk & 0xFFFF;
        const float p = __half2float(__ushort_as_half((unsigned short)(pk >> 16)));
        float sc = ss[s * 2] + st + cth * p;
        sc = fmaxf(sc, 0.2f * sc);
        const float ev = __expf(sc);
        const float2 G = __half22float2(pG[s * 16]);
        den  += ev;
        num0 += ev * G.x;
        num1 += ev * G.y;
    }

    // reduce across the 4 edge slots (lane bits 4,5)
    num0 += __shfl_xor(num0, 16, 64);
    num1 += __shfl_xor(num1, 16, 64);
    den  += __shfl_xor(den,  16, 64);
    num0 += __shfl_xor(num0, 32, 64);
    num1 += __shfl_xor(num1, 32, 64);
    den  += __shfl_xor(den,  32, 64);

    if (lane < 16) {
        const int h = g * 2 + hh;
        const int idx = n * HF + h * FO + f2 * 2;
        const float inv = 1.f / (den + 1e-16f);
        float2 o = *reinterpret_cast<const float2*>(&out[idx]);  // skip+bias
        float v0 = o.x + num0 * inv;
        float v1 = o.y + num1 * inv;
        v0 = v0 > 0.f ? v0 : expm1f(v0);
        v1 = v1 > 0.f ? v1 : expm1f(v1);
        *reinterpret_cast<float2*>(&out[idx]) = make_float2(v0, v1);
    }
}

// ---------------------------------------------------------------------------
extern "C" void kernel_launch(void* const* d_in, const int* in_sizes, int n_in,
                              void* d_out, int out_size, void* d_ws, size_t ws_size,
                              hipStream_t stream)
{
    const float* x     = (const float*)d_in[0];
    const int*   ei    = (const int*)d_in[1];
    const float* prob  = (const float*)d_in[2];
    const float* Wp    = (const float*)d_in[3];
    const float* Wt    = (const float*)d_in[4];
    const float* a_src = (const float*)d_in[5];
    const float* a_trg = (const float*)d_in[6];
    const float* a_tp  = (const float*)d_in[7];
    const float* Wskip = (const float*)d_in[8];
    const float* bias  = (const float*)d_in[9];
    float* out = (float*)d_out;

    const int E = in_sizes[2];        // edge_prob element count = E
    const int* src = ei;              // edge_index row 0
    const int* trg = ei + E;          // edge_index row 1

    // Workspace layout (~23 MB); all blocks 16B-aligned by construction
    char* wsb = (char*)d_ws;
    __half* projG  = (__half*)wsb;                      // Nn*HF f16 (12.8 MB)
    float* ssg     = (float*)(wsb + (size_t)Nn*HF*2);   // 4*Nn*2    (1.6 MB)
    float* stg     = ssg + (size_t)4 * Nn * 2;          // 4*Nn*2    (1.6 MB)
    float* ctp     = stg + (size_t)4 * Nn * 2;          // 16 floats
    _Float16* Wh   = (_Float16*)(ctp + 16);             // 272*128   (68 KB)
    unsigned int* spk = (unsigned int*)(Wh + (size_t)NWR * FIN); // E (3.2 MB)
    int*   deg     = (int*)(spk + E);                   // Nn
    int*   pos     = deg + Nn;                          // Nn
    int*   partial = pos + Nn;                          // NSCAN (pad 256)

    hipMemsetAsync(deg, 0, (size_t)Nn * sizeof(int), stream);
    k_count<<<(E / 4 + 255) / 256, 256, 0, stream>>>(trg, deg, Wt, a_tp, ctp, E);
    k_scan1<<<NSCAN, 256, 0, stream>>>(deg, partial);
    k_scan3<<<NSCAN, 256, 0, stream>>>(deg, partial, pos);
    k_fill<<<(E / 4 + 255) / 256, 256, 0, stream>>>(src, trg, prob, pos, spk, E);
    k_prep<<<NWR, 128, 0, stream>>>(Wp, Wskip, a_src, a_trg, Wh);
    k_node<<<Nn / 16, 64, 0, stream>>>(x, Wh, bias, projG, out, ssg, stg);
    k_gather<<<4 * (Nn / 4), 256, 0, stream>>>(spk, pos, ssg, stg, ctp,
                                               (const __half2*)projG, out);
}

// Round 11
// 182.157 us; speedup vs baseline: 1.2165x; 1.2165x over previous
//
#include <hip/hip_runtime.h>
#include <hip/hip_fp16.h>
#include <math.h>

// Problem constants (from reference)
constexpr int Nn  = 50000;   // nodes
constexpr int FIN = 128;     // input features
constexpr int NH  = 8;       // heads
constexpr int FO  = 16;      // features per head
constexpr int HF  = 128;     // NH*FO
constexpr int NWR = 272;     // Wh rows: Wp(128) | Wskip(128) | Va_src(8) | Va_trg(8)
constexpr int NSTRIPE = Nn / 16;                // 3125 node stripes
constexpr int NSCAN = (Nn + 255) / 256;         // 196 scan blocks

typedef _Float16 f16x8 __attribute__((ext_vector_type(8)));
typedef float    f32x4 __attribute__((ext_vector_type(4)));

// ---------------------------------------------------------------------------
// Weight prep (separate launch — node GEMM depends on Wh, so it must be
// complete before k_fused's node partition runs): Wh[272][128] f16 =
//   rows   0..127 : Wp
//   rows 128..255 : Wskip
//   rows 256..263 : Va_src[h][k] = sum_f a_src[h,f] * Wp[h*16+f][k]
//   rows 264..271 : Va_trg[h][k] = sum_f a_trg[h,f] * Wp[h*16+f][k]
// Also computes ctp[h] = <Wt[h,:], a_tp[h,:]> in block 0.
// ---------------------------------------------------------------------------
__global__ __launch_bounds__(256) void k_prep(
    const float* __restrict__ Wp, const float* __restrict__ Wskip,
    const float* __restrict__ a_src, const float* __restrict__ a_trg,
    const float* __restrict__ Wt, const float* __restrict__ a_tp,
    _Float16* __restrict__ Wh, float* __restrict__ ctp)
{
    if (blockIdx.x == 0 && threadIdx.x < NH) {
        int h = threadIdx.x;
        float s = 0.f;
        #pragma unroll
        for (int f = 0; f < FO; ++f) s += Wt[h * FO + f] * a_tp[h * FO + f];
        ctp[h] = s;
    }
    const int o = blockIdx.x * 2 + (threadIdx.x >> 7);  // 0..271
    const int k = threadIdx.x & 127;
    float v;
    if (o < 128)      v = Wp[o * FIN + k];
    else if (o < 256) v = Wskip[(o - 128) * FIN + k];
    else if (o < 264) {
        const int h = o - 256;
        float s = 0.f;
        #pragma unroll
        for (int f = 0; f < FO; ++f)
            s += a_src[h * FO + f] * Wp[(h * FO + f) * FIN + k];
        v = s;
    } else {
        const int h = o - 264;
        float s = 0.f;
        #pragma unroll
        for (int f = 0; f < FO; ++f)
            s += a_trg[h * FO + f] * Wp[(h * FO + f) * FIN + k];
        v = s;
    }
    Wh[o * FIN + k] = (_Float16)v;
}

// ---------------------------------------------------------------------------
// Fused count + node GEMM (truly independent: count reads trg, writes deg;
// node reads x/Wh, writes projA/out/s_pair):
//   blocks [0, nbCount)   : CSR degree count
//   blocks [nbCount, end) : node GEMM via MFMA (4 waves/block)
// ---------------------------------------------------------------------------
__global__ __launch_bounds__(256) void k_fused(
    const int* __restrict__ trg, int* __restrict__ deg,
    const _Float16* __restrict__ Wh,
    const float* __restrict__ x, const float* __restrict__ bias,
    __half* __restrict__ projA, float* __restrict__ out,
    float* __restrict__ s_pair,
    int E, int nbCount)
{
    const int bid = blockIdx.x;

    if (bid < nbCount) {
        int e4 = bid * 256 + threadIdx.x;
        if (e4 * 4 < E) {
            int4 t = reinterpret_cast<const int4*>(trg)[e4];
            atomicAdd(&deg[t.x], 1);
            atomicAdd(&deg[t.y], 1);
            atomicAdd(&deg[t.z], 1);
            atomicAdd(&deg[t.w], 1);
        }
        return;
    }

    // ---- node GEMM: one wave per 16-node stripe, C = x @ Wh^T ----
    const int stripe = (bid - nbCount) * 4 + (threadIdx.x >> 6);
    if (stripe >= NSTRIPE) return;
    const int n0 = stripe * 16;
    const int l  = threadIdx.x & 63;
    const int lr = l & 15;
    const int kb = l >> 4;                     // k-block 0..3

    f16x8 a[4];
    const float* xr = x + (size_t)(n0 + lr) * FIN + kb * 8;
    #pragma unroll
    for (int ks = 0; ks < 4; ++ks) {
        float4 u0 = *reinterpret_cast<const float4*>(xr + ks * 32);
        float4 u1 = *reinterpret_cast<const float4*>(xr + ks * 32 + 4);
        a[ks][0] = (_Float16)u0.x; a[ks][1] = (_Float16)u0.y;
        a[ks][2] = (_Float16)u0.z; a[ks][3] = (_Float16)u0.w;
        a[ks][4] = (_Float16)u1.x; a[ks][5] = (_Float16)u1.y;
        a[ks][6] = (_Float16)u1.z; a[ks][7] = (_Float16)u1.w;
    }

    f32x4 acc[17];
    #pragma unroll
    for (int t = 0; t < 17; ++t) acc[t] = (f32x4){0.f, 0.f, 0.f, 0.f};

    const _Float16* wb = Wh + (size_t)lr * FIN + kb * 8;
    #pragma unroll
    for (int t = 0; t < 17; ++t) {
        const _Float16* wt = wb + (size_t)t * 16 * FIN;
        #pragma unroll
        for (int ks = 0; ks < 4; ++ks) {
            f16x8 b = *reinterpret_cast<const f16x8*>(wt + ks * 32);
            acc[t] = __builtin_amdgcn_mfma_f32_16x16x32_f16(a[ks], b, acc[t], 0, 0, 0);
        }
    }

    #pragma unroll
    for (int r = 0; r < 4; ++r) {
        const int n = n0 + kb * 4 + r;
        // proj heads (tiles 0..7), node-major f16: projA[n][t][lr]
        #pragma unroll
        for (int t = 0; t < 8; ++t)
            projA[(size_t)n * HF + t * FO + lr] = __float2half_rn(acc[t][r]);
        // skip + bias (tiles 8..15) -> output accumulator
        #pragma unroll
        for (int t = 8; t < 16; ++t) {
            const int o = (t - 8) * 16 + lr;
            out[(size_t)n * HF + o] = acc[t][r] + bias[o];
        }
        // score tile 16: cols 0..7 = s_src per head, 8..15 = s_trg per head
        s_pair[n * 16 + lr] = acc[16][r];
    }
}

// ---------------------------------------------------------------------------
// Scan: per-block sums, then fused (redundant block-scan of partials) +
// per-element exclusive scan -> pos.
// ---------------------------------------------------------------------------
__global__ __launch_bounds__(256) void k_scan1(const int* __restrict__ deg,
                                               int* __restrict__ partial)
{
    __shared__ int lds[256];
    int t = threadIdx.x, i = blockIdx.x * 256 + t;
    lds[t] = (i < Nn) ? deg[i] : 0;
    __syncthreads();
    for (int off = 128; off > 0; off >>= 1) {
        if (t < off) lds[t] += lds[t + off];
        __syncthreads();
    }
    if (t == 0) partial[blockIdx.x] = lds[0];
}

__global__ __launch_bounds__(256) void k_scan3(const int* __restrict__ deg,
                                               const int* __restrict__ partial,
                                               int* __restrict__ pos)
{
    __shared__ int lds[256], lds2[256];
    const int t = threadIdx.x;
    const int i = blockIdx.x * 256 + t;
    lds2[t] = (t < NSCAN) ? partial[t] : 0;
    __syncthreads();
    for (int off = 1; off < 256; off <<= 1) {
        int u = (t >= off) ? lds2[t - off] : 0;
        __syncthreads();
        lds2[t] += u;
        __syncthreads();
    }
    const int base = (blockIdx.x == 0) ? 0 : lds2[blockIdx.x - 1];
    int v = (i < Nn) ? deg[i] : 0;
    lds[t] = v;
    __syncthreads();
    for (int off = 1; off < 256; off <<= 1) {
        int u = (t >= off) ? lds[t - off] : 0;
        __syncthreads();
        lds[t] += u;
        __syncthreads();
    }
    if (i < Nn) pos[i] = base + lds[t] - v;
}

// fill: pos[n] bumps exclusive -> inclusive; row n spans
// [ (n ? pos[n-1] : 0), pos[n] ).  spk = src(16b) | f16(prob)(16b), 4B/edge.
__global__ __launch_bounds__(256) void k_fill(
    const int* __restrict__ src, const int* __restrict__ trg,
    const float* __restrict__ prob, int* __restrict__ pos,
    unsigned int* __restrict__ spk, int E)
{
    int e4 = blockIdx.x * blockDim.x + threadIdx.x;
    if (e4 * 4 >= E) return;
    int4   s4 = reinterpret_cast<const int4*>(src)[e4];
    int4   t4 = reinterpret_cast<const int4*>(trg)[e4];
    float4 p4 = reinterpret_cast<const float4*>(prob)[e4];
    int    sv[4] = {s4.x, s4.y, s4.z, s4.w};
    int    tv[4] = {t4.x, t4.y, t4.z, t4.w};
    float  pv[4] = {p4.x, p4.y, p4.z, p4.w};
    #pragma unroll
    for (int i = 0; i < 4; ++i) {
        int slot = atomicAdd(&pos[tv[i]], 1);
        spk[slot] = (unsigned int)sv[i] |
            ((unsigned int)__half_as_ushort(__float2half_rn(pv[i])) << 16);
    }
}

// ---------------------------------------------------------------------------
// Fused gather (R8 structure): one wave per node; lanes = 8 heads x 8
// feature-pairs. All lanes share the node's edge range (zero divergence,
// zero shuffles). Per edge: spk dword (broadcast) + s_pair[s] gather +
// projA[s] 256B contiguous wave-read; score+exp inline. 4 independent
// chains for memory-level parallelism.
// ---------------------------------------------------------------------------
__global__ __launch_bounds__(256) void k_gather(
    const unsigned int* __restrict__ spk, const int* __restrict__ pos,
    const float* __restrict__ s_pair, const float* __restrict__ ctp,
    const __half2* __restrict__ projA, float* __restrict__ out)
{
    const int wv   = threadIdx.x >> 6;
    const int n    = blockIdx.x * 4 + wv;      // 12500*4 = 50000 exactly
    const int lane = threadIdx.x & 63;
    const int h    = lane >> 3;                // head 0..7
    const int f2   = lane & 7;                 // feature pair 0..7

    const int jb = (n == 0) ? 0 : pos[n - 1];
    const int je = pos[n];
    const float st  = s_pair[n * 16 + 8 + h];
    const float cth = ctp[h];
    const float* __restrict__ ssl = s_pair + h;          // [s*16]
    const __half2* __restrict__ pA = projA + h * 8 + f2; // [s*64]

    float num0 = 0.f, num1 = 0.f, den = 0.f;
    int j = jb;
    for (; j + 3 < je; j += 4) {               // 4 independent chains
        const unsigned int pk0 = spk[j];
        const unsigned int pk1 = spk[j + 1];
        const unsigned int pk2 = spk[j + 2];
        const unsigned int pk3 = spk[j + 3];
        const int s0 = pk0 & 0xFFFF, s1 = pk1 & 0xFFFF;
        const int s2 = pk2 & 0xFFFF, s3 = pk3 & 0xFFFF;
        const float ss0 = ssl[s0 * 16], ss1 = ssl[s1 * 16];
        const float ss2 = ssl[s2 * 16], ss3 = ssl[s3 * 16];
        const __half2 g0 = pA[s0 * 64], g1 = pA[s1 * 64];
        const __half2 g2 = pA[s2 * 64], g3 = pA[s3 * 64];
        const float p0 = __half2float(__ushort_as_half((unsigned short)(pk0 >> 16)));
        const float p1 = __half2float(__ushort_as_half((unsigned short)(pk1 >> 16)));
        const float p2 = __half2float(__ushort_as_half((unsigned short)(pk2 >> 16)));
        const float p3 = __half2float(__ushort_as_half((unsigned short)(pk3 >> 16)));
        float sc0 = ss0 + st + cth * p0;
        float sc1 = ss1 + st + cth * p1;
        float sc2 = ss2 + st + cth * p2;
        float sc3 = ss3 + st + cth * p3;
        sc0 = fmaxf(sc0, 0.2f * sc0);          // leaky_relu(0.2)
        sc1 = fmaxf(sc1, 0.2f * sc1);
        sc2 = fmaxf(sc2, 0.2f * sc2);
        sc3 = fmaxf(sc3, 0.2f * sc3);
        const float ev0 = __expf(sc0), ev1 = __expf(sc1);
        const float ev2 = __expf(sc2), ev3 = __expf(sc3);
        const float2 G0 = __half22float2(g0), G1 = __half22float2(g1);
        const float2 G2 = __half22float2(g2), G3 = __half22float2(g3);
        den  += (ev0 + ev1) + (ev2 + ev3);
        num0 += ev0 * G0.x + ev1 * G1.x + ev2 * G2.x + ev3 * G3.x;
        num1 += ev0 * G0.y + ev1 * G1.y + ev2 * G2.y + ev3 * G3.y;
    }
    for (; j < je; ++j) {
        const unsigned int pk = spk[j];
        const int s = pk & 0xFFFF;
        const float p = __half2float(__ushort_as_half((unsigned short)(pk >> 16)));
        float sc = ssl[s * 16] + st + cth * p;
        sc = fmaxf(sc, 0.2f * sc);
        const float ev = __expf(sc);
        const float2 G = __half22float2(pA[s * 64]);
        den  += ev;
        num0 += ev * G.x;
        num1 += ev * G.y;
    }

    const float inv = 1.f / (den + 1e-16f);
    const int idx = n * HF + h * FO + f2 * 2;
    float2 o = *reinterpret_cast<const float2*>(&out[idx]);  // skip+bias
    float v0 = o.x + num0 * inv;
    float v1 = o.y + num1 * inv;
    v0 = v0 > 0.f ? v0 : expm1f(v0);
    v1 = v1 > 0.f ? v1 : expm1f(v1);
    *reinterpret_cast<float2*>(&out[idx]) = make_float2(v0, v1);
}

// ---------------------------------------------------------------------------
extern "C" void kernel_launch(void* const* d_in, const int* in_sizes, int n_in,
                              void* d_out, int out_size, void* d_ws, size_t ws_size,
                              hipStream_t stream)
{
    const float* x     = (const float*)d_in[0];
    const int*   ei    = (const int*)d_in[1];
    const float* prob  = (const float*)d_in[2];
    const float* Wp    = (const float*)d_in[3];
    const float* Wt    = (const float*)d_in[4];
    const float* a_src = (const float*)d_in[5];
    const float* a_trg = (const float*)d_in[6];
    const float* a_tp  = (const float*)d_in[7];
    const float* Wskip = (const float*)d_in[8];
    const float* bias  = (const float*)d_in[9];
    float* out = (float*)d_out;

    const int E = in_sizes[2];        // edge_prob element count = E
    const int* src = ei;              // edge_index row 0
    const int* trg = ei + E;          // edge_index row 1

    // Workspace layout (~20 MB); all blocks 16B-aligned by construction
    char* wsb = (char*)d_ws;
    __half* projA  = (__half*)wsb;                      // Nn*HF f16 (12.8 MB)
    float* s_pair  = (float*)(wsb + (size_t)Nn*HF*2);   // Nn*16     (3.2 MB)
    float* ctp     = s_pair + (size_t)Nn * 16;          // 16 floats
    _Float16* Wh   = (_Float16*)(ctp + 16);             // 272*128   (68 KB)
    unsigned int* spk = (unsigned int*)(Wh + (size_t)NWR * FIN); // E (3.2 MB)
    int*   deg     = (int*)(spk + E);                   // Nn
    int*   pos     = deg + Nn;                          // Nn
    int*   partial = pos + Nn;                          // NSCAN (pad 256)

    const int nbCount = (E / 4 + 255) / 256;            // 782 @ E=800000
    const int nbNode  = (NSTRIPE + 3) / 4;              // 782
    const int nbTotal = nbCount + nbNode;

    hipMemsetAsync(deg, 0, (size_t)Nn * sizeof(int), stream);
    k_prep<<<NWR / 2, 256, 0, stream>>>(Wp, Wskip, a_src, a_trg, Wt, a_tp,
                                        Wh, ctp);
    k_fused<<<nbTotal, 256, 0, stream>>>(trg, deg, Wh, x, bias,
                                         projA, out, s_pair, E, nbCount);
    k_scan1<<<NSCAN, 256, 0, stream>>>(deg, partial);
    k_scan3<<<NSCAN, 256, 0, stream>>>(deg, partial, pos);
    k_fill<<<(E / 4 + 255) / 256, 256, 0, stream>>>(src, trg, prob, pos, spk, E);
    k_gather<<<Nn / 4, 256, 0, stream>>>(spk, pos, s_pair, ctp,
                                         (const __half2*)projA, out);
}